// Round 3
// baseline (623.360 us; speedup 1.0000x reference)
//
#include <hip/hip_runtime.h>
#include <hip/hip_bf16.h>

// Problem constants
#define BB 32
#define TT 1500
#define TP 1536      // T padded to 12*128 for GEMM tiles
#define EE 512
#define HH 4
#define AA 512
#define NN 2048      // H*A
#define CC 10
#define KCONV 201
#define KAUG 576     // 512 enc + 40 conv + 24 zero pad (18 k-steps of 32)

typedef __attribute__((ext_vector_type(8))) __bf16 bf16x8;
typedef __attribute__((ext_vector_type(4))) float f32x4;

// ---------- helpers ----------
__device__ __forceinline__ unsigned short f2bf(float x) {
    unsigned int u = __float_as_uint(x);
    u = (u + 0x7fffu + ((u >> 16) & 1u)) >> 16;   // RNE, inputs always finite
    return (unsigned short)u;
}
__device__ __forceinline__ float bf2f(unsigned short u) {
    return __uint_as_float(((unsigned int)u) << 16);
}
__device__ __forceinline__ void glds16(const void* g, void* l) {
    __builtin_amdgcn_global_load_lds(
        (const __attribute__((address_space(1))) unsigned int*)g,
        (__attribute__((address_space(3))) unsigned int*)l, 16, 0, 0);
}
// tanh(x) = 1 - 2/(e^{2x}+1); v_exp_f32+v_rcp_f32, ~5 VALU insts.
__device__ __forceinline__ float tanh_fast(float x) {
    float e = __expf(x * 2.0f);
    return fmaf(-2.0f, __builtin_amdgcn_rcpf(e + 1.0f), 1.0f);
}

// Fused prep kernel: block-range dispatch of 5 independent phases.
#define PREP_DEC0   0
#define PREP_CONV0  1024
#define PREP_WT0    8704
#define PREP_PAD0   13312
#define PREP_ENC0   20404
#define PREP_TOTAL  44404

__global__ __launch_bounds__(256) void k_prep(
    const float* __restrict__ enc, const int* __restrict__ xl,
    const float* __restrict__ dec_out, const float* __restrict__ aw_step,
    const float* __restrict__ w_enc, const float* __restrict__ b_enc,
    const float* __restrict__ w_dec, const float* __restrict__ w_conv,
    const float* __restrict__ conv_k,
    unsigned short* __restrict__ Whi, unsigned short* __restrict__ Wlo,
    unsigned short* __restrict__ Ahi, unsigned short* __restrict__ Alo,
    float* __restrict__ dec_a) {
    __shared__ float sbuf[456 + KCONV];
    const int bid = blockIdx.x;
    const int tid = threadIdx.x;

    if (bid < PREP_CONV0) {
        // ---- dec: dec_a[b][n] = b_enc[n] + sum_d dec[b][d]*w_dec[h][d][a] ----
        const int b  = bid >> 5;
        const int n0 = (bid & 31) * 64;
        const int n  = n0 + (tid & 63);
        const int dg = tid >> 6;                   // 0..3, 128 d each
        const int h  = n >> 9, a = n & 511;
        const float* dp = dec_out + (size_t)b * 512 + dg * 128;
        const float* wp = w_dec + ((size_t)h * 512 + dg * 128) * 512 + a;
        float acc = 0.f;
#pragma unroll 8
        for (int d = 0; d < 128; ++d) acc += dp[d] * wp[(size_t)d * 512];
        sbuf[tid] = acc;
        __syncthreads();
        if (tid < 64) {
            float tot = sbuf[tid] + sbuf[tid + 64] + sbuf[tid + 128] + sbuf[tid + 192];
            dec_a[(size_t)b * NN + n0 + tid] = b_enc[n0 + tid] + tot;
        }
    } else if (bid < PREP_WT0) {
        // ---- conv: grouped 1D conv over aw_step -> A cols [512,552) ----
        int r = bid - PREP_CONV0;                  // 7680 = 6*40*32
        const int tch = r % 6;
        const int hc  = (r / 6) % 40;
        const int b   = r / 240;
        const int h   = hc / 10;
        const int t0  = tch * 256;
        float* sAw = sbuf;
        float* sK  = sbuf + 456;
        for (int i = tid; i < 456; i += 256) {
            int ts = t0 - 100 + i;
            sAw[i] = (ts >= 0 && ts < TT) ? aw_step[((size_t)b * TT + ts) * HH + h] : 0.f;
        }
        if (tid < KCONV) sK[tid] = conv_k[(size_t)hc * KCONV + tid];
        __syncthreads();
        int t = t0 + tid;
        if (t < TT) {
            float acc = 0.f;
            for (int k = 0; k < KCONV; ++k) acc += sAw[tid + k] * sK[k];
            size_t o = ((size_t)b * TP + t) * KAUG + 512 + hc;
            unsigned short hi = f2bf(acc);
            Ahi[o] = hi; Alo[o] = f2bf(acc - bf2f(hi));
        }
    } else if (bid < PREP_PAD0) {
        // ---- wt: W planes [N=2048][KAUG], hi/lo ----
        int idx = (bid - PREP_WT0) * 256 + tid;    // 1,179,648
        int n = idx / KAUG, k = idx % KAUG;
        int h = n >> 9, a = n & 511;
        float val = 0.f;
        if (k < 512) {
            val = w_enc[((size_t)h * 512 + k) * 512 + a];
        } else if (k < 552) {
            int j = k - 512; int h2 = j / 10, c = j % 10;
            if (h2 == h) val = w_conv[((size_t)h * 10 + c) * 512 + a];
        }
        unsigned short hi = f2bf(val);
        Whi[idx] = hi;
        Wlo[idx] = f2bf(val - bf2f(hi));
    } else if (bid < PREP_ENC0) {
        // ---- pad: zero rows >=1500 (all cols) + cols [552,576) (rows <1500) ----
        int idx = (bid - PREP_PAD0) * 256 + tid;
        const int tot1 = BB * 36 * KAUG;           // 663552
        const int tot2 = BB * TT * 24;             // 1152000
        size_t o;
        if (idx < tot1) {
            int b = idx / (36 * KAUG); int r2 = idx % (36 * KAUG);
            int t = 1500 + r2 / KAUG;  int k = r2 % KAUG;
            o = ((size_t)b * TP + t) * KAUG + k;
        } else if (idx < tot1 + tot2) {
            int j = idx - tot1;
            int b = j / (TT * 24); int r2 = j % (TT * 24);
            int t = r2 / 24;       int k = 552 + r2 % 24;
            o = ((size_t)b * TP + t) * KAUG + k;
        } else return;
        Ahi[o] = 0; Alo[o] = 0;
    } else {
        // ---- enc: f32 -> A planes cols [0,512); Alo for 256-granular heavy tiles ----
        long idx = (long)(bid - PREP_ENC0) * 256 + tid;   // 6,144,000 float4s
        if (idx >= 6144000L) return;
        long f = idx * 4;
        int b = (int)(f / 768000);
        int r2 = (int)(f % 768000);
        int t = r2 >> 9, e = r2 & 511;
        float4 vv = *reinterpret_cast<const float4*>(enc + f);
        ushort4 h4;
        h4.x = f2bf(vv.x); h4.y = f2bf(vv.y); h4.z = f2bf(vv.z); h4.w = f2bf(vv.w);
        size_t o = ((size_t)b * TP + t) * KAUG + e;
        *reinterpret_cast<ushort4*>(Ahi + o) = h4;
        if (((t & ~255) + 256) > xl[b]) {          // 256-row tile containing t is heavy
            ushort4 l4;
            l4.x = f2bf(vv.x - bf2f(h4.x));
            l4.y = f2bf(vv.y - bf2f(h4.y));
            l4.z = f2bf(vv.z - bf2f(h4.z));
            l4.w = f2bf(vv.w - bf2f(h4.w));
            *reinterpret_cast<ushort4*>(Alo + o) = l4;
        }
    }
}

// ---------- 256x256 GEMM, 4-phase interleave, 3-buffer counted-vmcnt pipeline ----------
// 512 thr / 8 waves (2M x 4N), per-wave 128x64 output, BK=32, acc[8][4] f32x4.
// Plane folding as before: nk=18 (valid) or 54 (heavy, 256-granular): seg0 Ahi*Whi,
// seg1 Ahi*Wlo, seg2 Alo*Whi.
// Per step: 4 phases, each { stage 1 of 4 pieces for step t+2 -> 2 ds_read_b128 ->
// 8 MFMA under setprio }; phase 0 also reads the 4 B-frags (reused all phases).
// Pieces: 0 = B rows 0-127, 1 = B rows 128-255, 2 = A rows 0-63 & 128-191 (what
// phases 0-1 read, both wm halves), 3 = A rows 64-127 & 192-255 (phases 2-3).
// Sync: ONE {s_waitcnt vmcnt(4); s_barrier} per step. vmcnt(4) leaves this wave's 4
// step-(t+2) loads in flight across the barrier (counted-vmcnt, never drain in loop)
// while guaranteeing all step-(t+1) pieces landed; barrier makes that guarantee
// cross-wave. Buffers mod 3: read t%3, write (t+2)%3 -- disjoint; the buffer being
// written was last read at step t-1, sealed by the intervening barrier.
// LDS swizzle (both-sides, rule #21): source chunk pre-swizzled via ko, read via fc.
// Block order: ntile = bid&7 (one ntile strip per XCD -> W slice L2-resident);
// mtile DESCENDING (heavy tiles first -> tail runs light 18-step blocks).
__global__ __launch_bounds__(512, 2) void k_gemm(
    const unsigned short* __restrict__ Ahi, const unsigned short* __restrict__ Alo,
    const unsigned short* __restrict__ Whi, const unsigned short* __restrict__ Wlo,
    const float* __restrict__ dec_a, const float* __restrict__ vvec,
    const int* __restrict__ xl, float* __restrict__ energy) {
    __shared__ unsigned short lsA[3][8192];   // [buf][256 rows x 32 cols]
    __shared__ unsigned short lsB[3][8192];
    const int bid = blockIdx.x;               // 1536 = 8 ntile * 6 mtile * 32 b
    const int ntile = bid & 7;
    const int rest = bid >> 3;
    const int mtile = 5 - (rest >> 5);        // heavy-first
    const int b = rest & 31;
    const int m0 = mtile * 256, n0 = ntile * 256;
    const int xlen = xl[b];
    const int nk = (m0 + 256 <= xlen) ? 18 : 54;

    const int tid = threadIdx.x;
    const int lane = tid & 63, wave = tid >> 6;
    const int wm = wave >> 2, wn = wave & 3;

    f32x4 acc[8][4];
#pragma unroll
    for (int i = 0; i < 8; i++)
#pragma unroll
        for (int j = 0; j < 4; j++) acc[i][j] = (f32x4){0.f, 0.f, 0.f, 0.f};

    const int r = tid >> 2;                   // 0..127 (piece-local row)
    const int rowP2 = r + (r & 64);           // piece2 rows: 0-63 & 128-191
    const int ko = ((tid & 3) ^ ((r >> 1) & 3)) * 8;   // pre-swizzled source chunk
    const size_t abase = ((size_t)b * TP + m0 + rowP2) * KAUG + ko;
    const size_t bbase = ((size_t)n0 + r) * KAUG + ko;
    const int ldstA = rowP2 * 32 + (tid & 3) * 8;      // linear-per-wave LDS dest
    const int ldstB = tid * 8;
    const int fc = ((lane >> 4) ^ ((lane >> 1) & 3)) * 8;
    const int arow0 = wm * 128 + (lane & 15);
    const int brow0 = wn * 64 + (lane & 15);

#define STG0(BUF, BP, K0) glds16((BP) + bbase + (K0), &lsB[BUF][ldstB])
#define STG1(BUF, BP, K0) glds16((BP) + bbase + (size_t)128 * KAUG + (K0), &lsB[BUF][ldstB + 4096])
#define STG2(BUF, AP, K0) glds16((AP) + abase + (K0), &lsA[BUF][ldstA])
#define STG3(BUF, AP, K0) glds16((AP) + abase + (size_t)64 * KAUG + (K0), &lsA[BUF][ldstA + 2048])
#define MFMA4(AF, AI) \
    acc[AI][0] = __builtin_amdgcn_mfma_f32_16x16x32_bf16(AF, bfr0, acc[AI][0], 0, 0, 0); \
    acc[AI][1] = __builtin_amdgcn_mfma_f32_16x16x32_bf16(AF, bfr1, acc[AI][1], 0, 0, 0); \
    acc[AI][2] = __builtin_amdgcn_mfma_f32_16x16x32_bf16(AF, bfr2, acc[AI][2], 0, 0, 0); \
    acc[AI][3] = __builtin_amdgcn_mfma_f32_16x16x32_bf16(AF, bfr3, acc[AI][3], 0, 0, 0);
#define PHASE(P) { \
    bf16x8 a0 = *(const bf16x8*)&lA[(arow0 + (2 * (P)) * 16) * 32 + fc]; \
    bf16x8 a1 = *(const bf16x8*)&lA[(arow0 + (2 * (P) + 1) * 16) * 32 + fc]; \
    __builtin_amdgcn_s_setprio(1); \
    MFMA4(a0, 2 * (P)); \
    MFMA4(a1, 2 * (P) + 1); \
    __builtin_amdgcn_s_setprio(0); }

    // prologue: stage steps 0 and 1 (both seg0: Ahi/Whi, k0 = 0 / 32)
    STG0(0, Whi, 0); STG1(0, Whi, 0); STG2(0, Ahi, 0); STG3(0, Ahi, 0);
    STG0(1, Whi, 32); STG1(1, Whi, 32); STG2(1, Ahi, 32); STG3(1, Ahi, 32);
    asm volatile("s_waitcnt vmcnt(4)" ::: "memory");
    __builtin_amdgcn_s_barrier();
    __builtin_amdgcn_sched_barrier(0);

    int bc = 0;
    for (int s = 0; s < nk; ++s) {
        const int sp = s + 2;
        const bool st = sp < nk;
        const int bp2 = (bc + 2 >= 3) ? bc - 1 : bc + 2;   // (s+2)%3
        const unsigned short* ApN = Ahi;
        const unsigned short* BpN = Whi;
        int k0n = 0;
        if (st) {
            const int seg = (sp >= 36) ? 2 : ((sp >= 18) ? 1 : 0);
            k0n = (sp - seg * 18) * 32;
            if (seg == 2) ApN = Alo;
            if (seg == 1) BpN = Wlo;
        }
        const unsigned short* lA = lsA[bc];
        const unsigned short* lB = lsB[bc];

        // phase 0: B-frag reads + A frags 0,1
        if (st) STG0(bp2, BpN, k0n);
        bf16x8 bfr0 = *(const bf16x8*)&lB[(brow0 + 0) * 32 + fc];
        bf16x8 bfr1 = *(const bf16x8*)&lB[(brow0 + 16) * 32 + fc];
        bf16x8 bfr2 = *(const bf16x8*)&lB[(brow0 + 32) * 32 + fc];
        bf16x8 bfr3 = *(const bf16x8*)&lB[(brow0 + 48) * 32 + fc];
        PHASE(0)
        // phase 1
        if (st) STG1(bp2, BpN, k0n);
        PHASE(1)
        // phase 2
        if (st) STG2(bp2, ApN, k0n);
        PHASE(2)
        // phase 3
        if (st) STG3(bp2, ApN, k0n);
        PHASE(3)

        if (s < nk - 1) {
            if (st) asm volatile("s_waitcnt vmcnt(4)" ::: "memory");
            else    asm volatile("s_waitcnt vmcnt(0)" ::: "memory");
            __builtin_amdgcn_s_barrier();
            __builtin_amdgcn_sched_barrier(0);
        }
        bc = (bc == 2) ? 0 : bc + 1;
    }
#undef STG0
#undef STG1
#undef STG2
#undef STG3
#undef MFMA4
#undef PHASE

    // Epilogue: x = acc + dec_a[b][n]; energy += tanh(x)*v[n], reduced over A-dim
    const int h = ntile >> 1;            // 256-wide tile lies inside one head (512)
    const int kg = lane >> 4;
    float dv[4], vv[4];
#pragma unroll
    for (int j = 0; j < 4; j++) {
        int ng = n0 + wn * 64 + j * 16 + (lane & 15);
        dv[j] = dec_a[(size_t)b * NN + ng];
        vv[j] = vvec[ng];
    }
#pragma unroll
    for (int i = 0; i < 8; i++) {
        float part[4] = {0.f, 0.f, 0.f, 0.f};
#pragma unroll
        for (int j = 0; j < 4; j++)
#pragma unroll
            for (int rr = 0; rr < 4; rr++)
                part[rr] += tanh_fast(acc[i][j][rr] + dv[j]) * vv[j];
#pragma unroll
        for (int rr = 0; rr < 4; rr++) {
            float s = part[rr];
            s += __shfl_xor(s, 1, 64);
            s += __shfl_xor(s, 2, 64);
            s += __shfl_xor(s, 4, 64);
            s += __shfl_xor(s, 8, 64);
            if ((lane & 15) == 0) {
                int t = m0 + wm * 128 + i * 16 + kg * 4 + rr;
                if (t < TT)
                    atomicAdd(&energy[((size_t)b * HH + h) * TP + t], s);
            }
        }
    }
}

// ---------- masked softmax over time (replicates energy * (+1 / -1024) mask) ----------
__global__ __launch_bounds__(512) void k_softmax(const float* __restrict__ energy,
                                                 const int* __restrict__ x_lens,
                                                 float* __restrict__ aw) {
    const int b = blockIdx.x >> 2, h = blockIdx.x & 3;
    const int tid = threadIdx.x;
    __shared__ float sE[TT];
    __shared__ float red[512];
    const int xlen = x_lens[b];
    float lmax = -3.4e38f;
    for (int t = tid; t < TT; t += 512) {
        float e = energy[((size_t)b * HH + h) * TP + t];
        float m = (t < xlen) ? e : e * -1024.0f;
        sE[t] = m;
        lmax = fmaxf(lmax, m);
    }
    red[tid] = lmax; __syncthreads();
    for (int s = 256; s > 0; s >>= 1) { if (tid < s) red[tid] = fmaxf(red[tid], red[tid + s]); __syncthreads(); }
    float mx = red[0]; __syncthreads();
    float lsum = 0.f;
    for (int t = tid; t < TT; t += 512) {
        float ex = expf(sE[t] - mx);
        sE[t] = ex; lsum += ex;
    }
    red[tid] = lsum; __syncthreads();
    for (int s = 256; s > 0; s >>= 1) { if (tid < s) red[tid] += red[tid + s]; __syncthreads(); }
    float sum = red[0];
    for (int t = tid; t < TT; t += 512)
        aw[((size_t)b * TT + t) * HH + h] = sE[t] / sum;
}

// ---------- ctx_h[b][h][e] = sum_t aw[b][t][h] * enc[b][t][e] ----------
__global__ __launch_bounds__(512) void k_ctx(const float* __restrict__ enc,
                                             const float* __restrict__ aw,
                                             float* __restrict__ ctx_h) {
    const int chunk = blockIdx.x, b = blockIdx.y;
    const int t0 = chunk * 64;
    const int nt = (TT - t0 < 64) ? (TT - t0) : 64;
    __shared__ float sA[64 * 4];
    const int tid = threadIdx.x;
    for (int i = tid; i < nt * 4; i += 512)
        sA[i] = aw[((size_t)b * TT + t0) * HH + i];
    __syncthreads();
    float a0 = 0.f, a1 = 0.f, a2 = 0.f, a3 = 0.f;
    const float* ep = enc + ((size_t)b * TT + t0) * EE + tid;
    if (nt == 64) {
#pragma unroll 8
        for (int tt = 0; tt < 64; ++tt) {
            float ev = ep[(size_t)tt * EE];
            a0 += sA[tt * 4 + 0] * ev; a1 += sA[tt * 4 + 1] * ev;
            a2 += sA[tt * 4 + 2] * ev; a3 += sA[tt * 4 + 3] * ev;
        }
    } else {
        for (int tt = 0; tt < nt; ++tt) {
            float ev = ep[(size_t)tt * EE];
            a0 += sA[tt * 4 + 0] * ev; a1 += sA[tt * 4 + 1] * ev;
            a2 += sA[tt * 4 + 2] * ev; a3 += sA[tt * 4 + 3] * ev;
        }
    }
    atomicAdd(&ctx_h[((size_t)b * HH + 0) * EE + tid], a0);
    atomicAdd(&ctx_h[((size_t)b * HH + 1) * EE + tid], a1);
    atomicAdd(&ctx_h[((size_t)b * HH + 2) * EE + tid], a2);
    atomicAdd(&ctx_h[((size_t)b * HH + 3) * EE + tid], a3);
}

// ---------- ctx = ctx_h @ w_mha + b_mha ----------
__global__ __launch_bounds__(256) void k_mha(const float* __restrict__ ctx_h,
                                             const float* __restrict__ w_mha,
                                             const float* __restrict__ b_mha,
                                             float* __restrict__ out) {
    __shared__ float sred[256];
    const int tid = threadIdx.x;
    const int b  = blockIdx.x >> 2;
    const int eo = ((blockIdx.x & 3) << 7) + (tid & 127);
    const int kg = tid >> 7;                   // 0..1, 1024 k each
    const float* c = ctx_h + (size_t)b * NN + kg * 1024;
    const float* w = w_mha + ((size_t)kg * 1024) * EE + eo;
    float acc = 0.f;
#pragma unroll 8
    for (int k = 0; k < 1024; ++k) acc += c[k] * w[(size_t)k * EE];
    sred[tid] = acc;
    __syncthreads();
    if (tid < 128)
        out[(size_t)b * EE + eo] = b_mha[eo] + sred[tid] + sred[tid + 128];
}

extern "C" void kernel_launch(void* const* d_in, const int* in_sizes, int n_in,
                              void* d_out, int out_size, void* d_ws, size_t ws_size,
                              hipStream_t stream) {
    (void)in_sizes; (void)n_in; (void)out_size;
    const float* enc    = (const float*)d_in[0];
    const int*   xlen   = (const int*)d_in[1];
    const float* dec    = (const float*)d_in[2];
    const float* aw_in  = (const float*)d_in[3];
    const float* w_enc  = (const float*)d_in[4];
    const float* b_enc  = (const float*)d_in[5];
    const float* w_dec  = (const float*)d_in[6];
    const float* w_conv = (const float*)d_in[7];
    const float* convk  = (const float*)d_in[8];
    const float* v      = (const float*)d_in[9];
    const float* w_mha  = (const float*)d_in[10];
    const float* b_mha  = (const float*)d_in[11];
    float* out = (float*)d_out;

    // ws layout (needs ~119.3 MB)
    char* ws = (char*)d_ws;
    unsigned short* Whi = (unsigned short*)ws;                          // 2,359,296 B
    unsigned short* Wlo = Whi + (size_t)NN * KAUG;                      // 2,359,296 B
    unsigned short* Ahi = (unsigned short*)(ws + 4718592);              // 56,623,104 B
    unsigned short* Alo = Ahi + (size_t)BB * TP * KAUG;                 // 56,623,104 B
    float* dec_a  = (float*)(ws + 117964800);                           //   262,144 B
    float* energy = (float*)(ws + 118226944);                           //   786,432 B
    float* ctx_h  = (float*)(ws + 119013376);                           //   262,144 B
    (void)ws_size;

    hipMemsetAsync(energy, 0, 786432 + 262144, stream);  // energy + ctx_h (contiguous)

    k_prep<<<dim3(PREP_TOTAL), 256, 0, stream>>>(enc, xlen, dec, aw_in, w_enc, b_enc,
                                                 w_dec, w_conv, convk,
                                                 Whi, Wlo, Ahi, Alo, dec_a);
    k_gemm<<<dim3(1536), 512, 0, stream>>>(Ahi, Alo, Whi, Wlo, dec_a, v, xlen, energy);
    k_softmax<<<dim3(BB * HH), 512, 0, stream>>>(energy, xlen, out + 16384);
    k_ctx <<<dim3(24, BB), 512, 0, stream>>>(enc, out + 16384, ctx_h);
    k_mha <<<dim3(128), 256, 0, stream>>>(ctx_h, w_mha, b_mha, out);
}